// Round 6
// baseline (136.022 us; speedup 1.0000x reference)
//
#include <hip/hip_runtime.h>

// B=8, S=4096, E=256, H=4, DK=64. Tokens = 32768.
// Head-mix "attention": 4 GEMMs (32768x256 @ 256x256) + per-token 4x4 softmax.
// Round-6: occupancy via 2-LDS-buffer liveness + in-register head-mix.
//   Interleaved col tiling: wave j owns cols {g*64 + j*16 + lh, g=0..3}.
//   => V accs hold all 4 heads at same within-head col; P-mix is in-register;
//   V and Y need no dedicated LDS. bufA = x->Q, bufB = K->Y.
//   LDS 35.8 KB -> 4 blocks/CU -> all 1024 blocks resident (16 waves/CU).

typedef __bf16 bf16x8 __attribute__((ext_vector_type(8)));
typedef __bf16 bf16x4 __attribute__((ext_vector_type(4)));
typedef float f32x4 __attribute__((ext_vector_type(4)));

#define LDW 264   // LDS row stride (bf16 elems): 256 + 8 pad

#define MFMA(a, b, c) __builtin_amdgcn_mfma_f32_16x16x32_bf16((a), (b), (c), 0, 0, 0)

// ---------- prep: pack W into fragment-contiguous bf16, interleaved-n ----------
// frag (p, j, g, kk): lane (lh=lane&15, lq=lane>>4) holds
//   W_p[g*64 + j*16 + lh][kk*32 + lq*8 .. +8)   (16 B)
// at Wpk[frag_id*512 + lane*8], frag_id = ((p*4+j)*4+g)*8+kk.
__global__ void pack_wfrag(const float* __restrict__ Wq, const float* __restrict__ Wk,
                           const float* __restrict__ Wv, const float* __restrict__ Wo,
                           __bf16* __restrict__ Wpk) {
  const int f    = blockIdx.x;          // 0..511
  const int lane = threadIdx.x;         // 0..63
  const int kk = f & 7;
  const int g  = (f >> 3) & 3;
  const int j  = (f >> 5) & 3;
  const int p  = f >> 7;
  const float* W = (p == 0) ? Wq : (p == 1) ? Wk : (p == 2) ? Wv : Wo;
  const int lh = lane & 15, lq = lane >> 4;
  const int n  = g * 64 + j * 16 + lh;
  const int k0 = kk * 32 + lq * 8;
  const float4 s0 = *(const float4*)&W[n * 256 + k0];
  const float4 s1 = *(const float4*)&W[n * 256 + k0 + 4];
  bf16x8 r;
  r[0] = (__bf16)s0.x; r[1] = (__bf16)s0.y; r[2] = (__bf16)s0.z; r[3] = (__bf16)s0.w;
  r[4] = (__bf16)s1.x; r[5] = (__bf16)s1.y; r[6] = (__bf16)s1.z; r[7] = (__bf16)s1.w;
  *(bf16x8*)&Wpk[(size_t)f * 512 + lane * 8] = r;
}

// C/D scatter (+bias) -> bf16 LDS; acc slot g maps to col g*64 + colbase + lh.
__device__ __forceinline__ void store_cd(__bf16* __restrict__ buf, const f32x4 acc[2][4],
                                         const float* __restrict__ bias,
                                         int colbase, int lh, int lq) {
  #pragma unroll
  for (int g = 0; g < 4; ++g) {
    int col = g * 64 + colbase + lh;
    float bb = bias ? bias[col] : 0.f;
    #pragma unroll
    for (int mf = 0; mf < 2; ++mf) {
      int r = mf * 16 + lq * 4;
      #pragma unroll
      for (int c = 0; c < 4; ++c)
        buf[(r + c) * LDW + col] = (__bf16)(acc[mf][g][c] + bb);
    }
  }
}

// One projection k-loop: acc[mf][g] += A(LDS) @ W(packed global), dbuf prefetch.
__device__ __forceinline__ void proj(const __bf16* __restrict__ a0p,
                                     const __bf16* __restrict__ a1p,
                                     const __bf16* __restrict__ wB,  // + (g*8+kk)*512 (lane folded)
                                     f32x4 acc[2][4]) {
  bf16x8 WB[2][4];
  #pragma unroll
  for (int g = 0; g < 4; ++g)
    WB[0][g] = *(const bf16x8*)(wB + (g * 8 + 0) * 512);
  #pragma unroll
  for (int kk = 0; kk < 8; ++kk) {
    const int cur = kk & 1, nxt = cur ^ 1;
    if (kk < 7) {
      #pragma unroll
      for (int g = 0; g < 4; ++g)
        WB[nxt][g] = *(const bf16x8*)(wB + (g * 8 + kk + 1) * 512);
    }
    bf16x8 a0 = *(const bf16x8*)(a0p + kk * 32);
    bf16x8 a1 = *(const bf16x8*)(a1p + kk * 32);
    #pragma unroll
    for (int g = 0; g < 4; ++g) {
      acc[0][g] = MFMA(a0, WB[cur][g], acc[0][g]);
      acc[1][g] = MFMA(a1, WB[cur][g], acc[1][g]);
    }
  }
}

__launch_bounds__(256, 4)
__global__ void fused_attn(const float* __restrict__ x, const __bf16* __restrict__ Wpk,
                           const float* __restrict__ bq, const float* __restrict__ bk,
                           const float* __restrict__ bv, const float* __restrict__ bo,
                           float* __restrict__ out) {
  __shared__ __bf16 sA[32 * LDW];   // x tile -> Q
  __shared__ __bf16 sB[32 * LDW];   // K -> Y
  __shared__ float PL[32 * 16];     // softmax probs [m][h][g]

  const int tid  = threadIdx.x;
  const int lane = tid & 63;
  const int nw   = tid >> 6;        // wave id = within-head col group j
  const int lh   = lane & 15;
  const int lq   = lane >> 4;
  const int cb   = nw * 16;         // colbase
  const int tok0 = blockIdx.x * 32;

  // ---- phase 1: stage x (lane-contiguous float4 -> bf16 padded LDS) ----
  const float4* xg = (const float4*)(x + (size_t)tok0 * 256);
  #pragma unroll
  for (int i = 0; i < 8; ++i) {
    int idx = i * 256 + tid;
    int row = idx >> 6;
    int c4  = idx & 63;
    float4 v = xg[idx];
    bf16x4 pk;
    pk[0] = (__bf16)v.x; pk[1] = (__bf16)v.y; pk[2] = (__bf16)v.z; pk[3] = (__bf16)v.w;
    *(bf16x4*)&sA[row * LDW + c4 * 4] = pk;
  }
  __syncthreads();

  const __bf16* a0p = sA + lh * LDW + lq * 8;
  const __bf16* a1p = a0p + 16 * LDW;
  const __bf16* wqB = Wpk + (size_t)((0 * 4 + nw) * 4 * 8) * 512 + lane * 8;
  const __bf16* wkB = Wpk + (size_t)((1 * 4 + nw) * 4 * 8) * 512 + lane * 8;
  const __bf16* wvB = Wpk + (size_t)((2 * 4 + nw) * 4 * 8) * 512 + lane * 8;
  const __bf16* woB = Wpk + (size_t)((3 * 4 + nw) * 4 * 8) * 512 + lane * 8;

  // ---- phase 2: Q, K, V k-loops (A from sA). K -> sB immediately; Q, V in regs ----
  f32x4 qa[2][4];
  #pragma unroll
  for (int mf = 0; mf < 2; ++mf)
    #pragma unroll
    for (int g = 0; g < 4; ++g) qa[mf][g] = (f32x4){0.f, 0.f, 0.f, 0.f};
  proj(a0p, a1p, wqB, qa);

  {
    f32x4 ka[2][4];
    #pragma unroll
    for (int mf = 0; mf < 2; ++mf)
      #pragma unroll
      for (int g = 0; g < 4; ++g) ka[mf][g] = (f32x4){0.f, 0.f, 0.f, 0.f};
    proj(a0p, a1p, wkB, ka);
    store_cd(sB, ka, bk, cb, lh, lq);   // sB unread until scores; own cols only
  }

  f32x4 va[2][4];
  #pragma unroll
  for (int mf = 0; mf < 2; ++mf)
    #pragma unroll
    for (int g = 0; g < 4; ++g) va[mf][g] = (f32x4){0.f, 0.f, 0.f, 0.f};
  proj(a0p, a1p, wvB, va);
  // V bias (per acc slot g, col = g*64 + cb + lh; same for all 4 row-components)
  #pragma unroll
  for (int g = 0; g < 4; ++g) {
    float bb = bv[g * 64 + cb + lh];
    #pragma unroll
    for (int mf = 0; mf < 2; ++mf)
      #pragma unroll
      for (int c = 0; c < 4; ++c) va[mf][g][c] += bb;
  }
  __syncthreads();   // all waves done reading x from sA

  // ---- phase 3: Q -> sA (x dead) ----
  store_cd(sA, qa, bq, cb, lh, lq);
  __syncthreads();   // Q, K visible

  // ---- phase 4: scores + softmax (4 active threads of 8 per token) ----
  {
    const int m   = tid >> 3;
    const int sub = tid & 7;
    if (sub < 4) {
      const int h = sub;
      float d0 = 0.f, d1 = 0.f, d2 = 0.f, d3 = 0.f;
      #pragma unroll
      for (int i = 0; i < 8; ++i) {
        bf16x8 qv = *(const bf16x8*)&sA[m * LDW + h * 64 + i * 8];
        bf16x8 k0 = *(const bf16x8*)&sB[m * LDW +   0 + i * 8];
        bf16x8 k1 = *(const bf16x8*)&sB[m * LDW +  64 + i * 8];
        bf16x8 k2 = *(const bf16x8*)&sB[m * LDW + 128 + i * 8];
        bf16x8 k3 = *(const bf16x8*)&sB[m * LDW + 192 + i * 8];
        #pragma unroll
        for (int c = 0; c < 8; ++c) {
          float qf = (float)qv[c];
          d0 += qf * (float)k0[c];
          d1 += qf * (float)k1[c];
          d2 += qf * (float)k2[c];
          d3 += qf * (float)k3[c];
        }
      }
      d0 *= 0.125f; d1 *= 0.125f; d2 *= 0.125f; d3 *= 0.125f;  // 1/sqrt(64)
      float mx = fmaxf(fmaxf(d0, d1), fmaxf(d2, d3));
      float e0 = expf(d0 - mx), e1 = expf(d1 - mx), e2 = expf(d2 - mx), e3 = expf(d3 - mx);
      float inv = 1.0f / (e0 + e1 + e2 + e3);
      float* pl = &PL[m * 16 + h * 4];
      pl[0] = e0 * inv; pl[1] = e1 * inv; pl[2] = e2 * inv; pl[3] = e3 * inv;
    }
  }
  __syncthreads();   // PL visible; K reads complete (sB reusable)

  // ---- prefetch first two O k-slices (overlaps mix + barrier) ----
  bf16x8 WB[2][4];
  #pragma unroll
  for (int g = 0; g < 4; ++g) {
    WB[0][g] = *(const bf16x8*)(woB + (g * 8 + 0) * 512);
    WB[1][g] = *(const bf16x8*)(woB + (g * 8 + 1) * 512);
  }

  // ---- phase 5: in-register head-mix, then Y -> sB ----
  {
    f32x4 ya[2][4];
    #pragma unroll
    for (int mf = 0; mf < 2; ++mf) {
      #pragma unroll
      for (int c = 0; c < 4; ++c) {
        int m = mf * 16 + lq * 4 + c;
        const f32x4 p0 = *(const f32x4*)&PL[m * 16 +  0];  // h=0: P[m][0][g]
        const f32x4 p1 = *(const f32x4*)&PL[m * 16 +  4];
        const f32x4 p2 = *(const f32x4*)&PL[m * 16 +  8];
        const f32x4 p3 = *(const f32x4*)&PL[m * 16 + 12];
        ya[mf][0][c] = p0[0]*va[mf][0][c] + p0[1]*va[mf][1][c] + p0[2]*va[mf][2][c] + p0[3]*va[mf][3][c];
        ya[mf][1][c] = p1[0]*va[mf][0][c] + p1[1]*va[mf][1][c] + p1[2]*va[mf][2][c] + p1[3]*va[mf][3][c];
        ya[mf][2][c] = p2[0]*va[mf][0][c] + p2[1]*va[mf][1][c] + p2[2]*va[mf][2][c] + p2[3]*va[mf][3][c];
        ya[mf][3][c] = p3[0]*va[mf][0][c] + p3[1]*va[mf][1][c] + p3[2]*va[mf][2][c] + p3[3]*va[mf][3][c];
      }
    }
    store_cd(sB, ya, nullptr, cb, lh, lq);   // Y at absolute cols (slot h -> h*64+cb+lh)
  }
  __syncthreads();   // Y visible

  // ---- phase 6: O-GEMM (A from sB), distance-2 prefetch into WB[cur] ----
  {
    const __bf16* yp0 = sB + lh * LDW + lq * 8;
    const __bf16* yp1 = yp0 + 16 * LDW;
    f32x4 acc[2][4];
    #pragma unroll
    for (int mf = 0; mf < 2; ++mf)
      #pragma unroll
      for (int g = 0; g < 4; ++g) acc[mf][g] = (f32x4){0.f, 0.f, 0.f, 0.f};

    #pragma unroll
    for (int kk = 0; kk < 8; ++kk) {
      const int cur = kk & 1;
      bf16x8 a0 = *(const bf16x8*)(yp0 + kk * 32);
      bf16x8 a1 = *(const bf16x8*)(yp1 + kk * 32);
      #pragma unroll
      for (int g = 0; g < 4; ++g) {
        acc[0][g] = MFMA(a0, WB[cur][g], acc[0][g]);
        acc[1][g] = MFMA(a1, WB[cur][g], acc[1][g]);
      }
      if (kk < 6) {
        #pragma unroll
        for (int g = 0; g < 4; ++g)
          WB[cur][g] = *(const bf16x8*)(woB + (g * 8 + kk + 2) * 512);
      }
    }

    #pragma unroll
    for (int g = 0; g < 4; ++g) {
      int col = g * 64 + cb + lh;
      float bb = bo[col];
      #pragma unroll
      for (int mf = 0; mf < 2; ++mf) {
        int rbase = tok0 + mf * 16 + lq * 4;
        #pragma unroll
        for (int c = 0; c < 4; ++c)
          out[(size_t)(rbase + c) * 256 + col] = acc[mf][g][c] + bb;
      }
    }
  }
}

extern "C" void kernel_launch(void* const* d_in, const int* in_sizes, int n_in,
                              void* d_out, int out_size, void* d_ws, size_t ws_size,
                              hipStream_t stream) {
  const float* x  = (const float*)d_in[0];
  const float* Wq = (const float*)d_in[1];
  const float* bq = (const float*)d_in[2];
  const float* Wk = (const float*)d_in[3];
  const float* bk = (const float*)d_in[4];
  const float* Wv = (const float*)d_in[5];
  const float* bv = (const float*)d_in[6];
  const float* Wo = (const float*)d_in[7];
  const float* bo = (const float*)d_in[8];
  float* out = (float*)d_out;
  __bf16* Wpk = (__bf16*)d_ws;   // 512 frags x 1 KB

  pack_wfrag<<<dim3(512), dim3(64), 0, stream>>>(Wq, Wk, Wv, Wo, Wpk);
  fused_attn<<<dim3(1024), dim3(256), 0, stream>>>(x, Wpk, bq, bk, bv, bo, out);
}